// Round 12
// baseline (165.227 us; speedup 1.0000x reference)
//
#include <hip/hip_runtime.h>
#include <math.h>

// HadamardProj: out[b,o] = -scale * (x[b]/(||x[b]||+eps)) . H[o,:] + bias[o]
// H[o,i] = (-1)^popcount(o&i), i<2048  =>  H row o == H row (o mod 2048)
// => y[b] = FWHT_2048(x[b]) (Sylvester), out[b,o] = -scale*inv_norm*y[o&2047] + bias[o]
//
// R12: packed-f16 FWHT. Lane owns e = j*256 + lane*4 + c; elements packed as
// h2 pairs (c0,c1),(c2,c3) -> 16 dwords/lane. All butterflies are v_pk_add_f16:
//   h=1,2 in-pack; h=4..128 shuffle stages on 16 dwords (96 swizzles, half of f32);
//   h=256..1024 reg-xor (16 pk-ops/stage). Shuffle butterfly via sign-XOR:
//   v' = partner + (v ^ sm), sm = hi-lane ? 0x80008000 : 0  (2 ops/dword).
// Norm computed in f32 from the original loads (exact); f16 only inside the
// transform: |err| ~ eps_f16*sqrt(11)*|y|*scale ~ 2e-5 << 1.28e-3 threshold.
// Epilogue: unpack to f32 once, direct vec4 stores (no y-LDS, no barrier);
// bias staged once per block as bf16 in LDS (20 KB).

typedef float f32x4 __attribute__((ext_vector_type(4)));
typedef _Float16 h2 __attribute__((ext_vector_type(2)));
typedef unsigned short u16x4 __attribute__((ext_vector_type(4)));

constexpr int N_IN  = 2048;   // 2^11
constexpr int N_OUT = 10000;

static __device__ __forceinline__ unsigned h2u(h2 v) { return __builtin_bit_cast(unsigned, v); }
static __device__ __forceinline__ h2 u2h(unsigned u) { return __builtin_bit_cast(h2, u); }

__global__ __launch_bounds__(256, 4) void fwht_proj_kernel(
    const float* __restrict__ x,
    const float* __restrict__ scale,
    const float* __restrict__ bias,
    float* __restrict__ out)
{
    __shared__ unsigned short blds[N_OUT];   // bf16 bias: 20,000 B

    // Stage bias once per block, f32 -> bf16 (RNE)
    {
        const f32x4* __restrict__ b4 = reinterpret_cast<const f32x4*>(bias);
        for (int i = threadIdx.x; i < N_OUT / 4; i += 256) {
            const f32x4 b = b4[i];
            u16x4 h;
            unsigned u;
            u = __float_as_uint(b.x); h.x = (unsigned short)((u + 0x7FFF + ((u >> 16) & 1)) >> 16);
            u = __float_as_uint(b.y); h.y = (unsigned short)((u + 0x7FFF + ((u >> 16) & 1)) >> 16);
            u = __float_as_uint(b.z); h.z = (unsigned short)((u + 0x7FFF + ((u >> 16) & 1)) >> 16);
            u = __float_as_uint(b.w); h.w = (unsigned short)((u + 0x7FFF + ((u >> 16) & 1)) >> 16);
            *reinterpret_cast<u16x4*>(&blds[i << 2]) = h;
        }
    }
    __syncthreads();

    const int wave = threadIdx.x >> 6;
    const int lane = threadIdx.x & 63;
    const size_t row = (size_t)blockIdx.x * 4 + wave;   // rows % 4 == 0
    const float* __restrict__ xrow = x + row * N_IN;

    // ---- load (f32), sum of squares in f32 (exact), pack to f16 ----
    h2 P[16];   // P[2j]=(c0,c1), P[2j+1]=(c2,c3) for e = j*256 + lane*4 + c
    float ss = 0.0f;
#pragma unroll
    for (int j = 0; j < 8; ++j) {
        const f32x4 L = *reinterpret_cast<const f32x4*>(xrow + (j << 8) + (lane << 2));
        ss = fmaf(L.x, L.x, ss);
        ss = fmaf(L.y, L.y, ss);
        ss = fmaf(L.z, L.z, ss);
        ss = fmaf(L.w, L.w, ss);
        h2 a, b;
        a.x = (_Float16)L.x;  a.y = (_Float16)L.y;
        b.x = (_Float16)L.z;  b.y = (_Float16)L.w;
        P[2 * j] = a;  P[2 * j + 1] = b;
    }
#pragma unroll
    for (int m = 1; m < 64; m <<= 1)
        ss += __shfl_xor(ss, m, 64);
    const float inv = 1.0f / (sqrtf(ss) + 1e-8f);   // matches x/(norm+eps)

    // ---- stage h=1 (bit0): intra-pack (a+b, a-b) ----
#pragma unroll
    for (int k = 0; k < 16; ++k) {
        h2 t;
        t.x = P[k].x + P[k].y;
        t.y = P[k].x - P[k].y;
        P[k] = t;
    }
    // ---- stage h=2 (bit1): between the two packs of each j ----
#pragma unroll
    for (int j = 0; j < 8; ++j) {
        const h2 a = P[2 * j], b = P[2 * j + 1];
        P[2 * j]     = a + b;
        P[2 * j + 1] = a - b;
    }
    // ---- stages h=4..128 (lane bits): shuffle butterflies, sign-XOR form ----
#pragma unroll
    for (int m = 1; m <= 32; m <<= 1) {
        const unsigned sm = (lane & m) ? 0x80008000u : 0u;
#pragma unroll
        for (int k = 0; k < 16; ++k) {
            const unsigned pv = __shfl_xor(h2u(P[k]), m, 64);
            P[k] = u2h(pv) + u2h(h2u(P[k]) ^ sm);
        }
    }
    // ---- stages h=256,512,1024 (j bits): register-index xor, packed ----
#pragma unroll
    for (int mj = 1; mj <= 4; mj <<= 1) {
#pragma unroll
        for (int j = 0; j < 8; ++j) {
            if ((j & mj) == 0) {
#pragma unroll
                for (int t = 0; t < 2; ++t) {
                    const h2 a = P[2 * j + t], b = P[2 * (j ^ mj) + t];
                    P[2 * j + t]          = a + b;
                    P[2 * (j ^ mj) + t]   = a - b;
                }
            }
        }
    }

    // ---- unpack once to f32 ----
    f32x4 Y[8];
#pragma unroll
    for (int j = 0; j < 8; ++j) {
        Y[j].x = (float)P[2 * j].x;
        Y[j].y = (float)P[2 * j].y;
        Y[j].z = (float)P[2 * j + 1].x;
        Y[j].w = (float)P[2 * j + 1].y;
    }

    const float s = -scale[0] * inv;   // fold norm + negated scale
    float* __restrict__ orow = out + row * N_OUT;

    // ---- epilogue: direct vec4 stores from regs; bf16 bias from LDS ----
#pragma unroll
    for (int w = 0; w < 4; ++w) {
#pragma unroll 2
        for (int j = 0; j < 8; ++j) {
            const int o = (w << 11) + (j << 8) + (lane << 2);
            const u16x4 h = *reinterpret_cast<const u16x4*>(&blds[o]);
            f32x4 r;
            r.x = fmaf(s, Y[j].x, __uint_as_float((unsigned)h.x << 16));
            r.y = fmaf(s, Y[j].y, __uint_as_float((unsigned)h.y << 16));
            r.z = fmaf(s, Y[j].z, __uint_as_float((unsigned)h.z << 16));
            r.w = fmaf(s, Y[j].w, __uint_as_float((unsigned)h.w << 16));
            *reinterpret_cast<f32x4*>(orow + o) = r;
        }
    }
    // partial window w=4: j=0..6 full, j=7 lanes 0..3
#pragma unroll 2
    for (int j = 0; j < 7; ++j) {
        const int o = 8192 + (j << 8) + (lane << 2);
        const u16x4 h = *reinterpret_cast<const u16x4*>(&blds[o]);
        f32x4 r;
        r.x = fmaf(s, Y[j].x, __uint_as_float((unsigned)h.x << 16));
        r.y = fmaf(s, Y[j].y, __uint_as_float((unsigned)h.y << 16));
        r.z = fmaf(s, Y[j].z, __uint_as_float((unsigned)h.z << 16));
        r.w = fmaf(s, Y[j].w, __uint_as_float((unsigned)h.w << 16));
        *reinterpret_cast<f32x4*>(orow + o) = r;
    }
    if (lane < 4) {
        const int o = 9984 + (lane << 2);
        const u16x4 h = *reinterpret_cast<const u16x4*>(&blds[o]);
        f32x4 r;
        r.x = fmaf(s, Y[7].x, __uint_as_float((unsigned)h.x << 16));
        r.y = fmaf(s, Y[7].y, __uint_as_float((unsigned)h.y << 16));
        r.z = fmaf(s, Y[7].z, __uint_as_float((unsigned)h.z << 16));
        r.w = fmaf(s, Y[7].w, __uint_as_float((unsigned)h.w << 16));
        *reinterpret_cast<f32x4*>(orow + o) = r;
    }
}

extern "C" void kernel_launch(void* const* d_in, const int* in_sizes, int n_in,
                              void* d_out, int out_size, void* d_ws, size_t ws_size,
                              hipStream_t stream) {
    const float* x     = (const float*)d_in[0];
    // d_in[1] = proj: unused — Hadamard structure computed via FWHT
    const float* scale = (const float*)d_in[2];
    const float* bias  = (const float*)d_in[3];
    float* out = (float*)d_out;

    const int rows = in_sizes[0] / N_IN;            // 16384
    dim3 grid(rows / 4), block(256);                // 4096 blocks
    hipLaunchKernelGGL(fwht_proj_kernel, grid, block, 0, stream,
                       x, scale, bias, out);
}

// Round 13
// 160.859 us; speedup vs baseline: 1.0272x; 1.0272x over previous
//
#include <hip/hip_runtime.h>
#include <math.h>

// HadamardProj: out[b,o] = -scale * (x[b]/(||x[b]||+eps)) . H[o,:] + bias[o]
// H[o,i] = (-1)^popcount(o&i), i<2048  =>  H row o == H row (o mod 2048)
// => y[b] = FWHT_2048(x[b]) (Sylvester), out[b,o] = -scale*inv_norm*y[o&2047] + bias[o]
//
// R13 = R10 (best, 160.2us: one wave-private LDS transpose replaces 6 shuffle
// stages) + bias staged per-block in LDS as bf16 (R5's proven fix for bias
// re-reads leaking past L2 under the 655 MB write stream). 52.8 KB LDS ->
// 3 blocks/CU (12 waves/CU); fills prove write BW doesn't need occupancy.

typedef float f32x4 __attribute__((ext_vector_type(4)));
typedef unsigned short u16x4 __attribute__((ext_vector_type(4)));

constexpr int N_IN  = 2048;   // 2^11
constexpr int N_OUT = 10000;

__device__ __forceinline__ int swz(int a) {   // float-index swizzle, involution
    return a ^ ((((a >> 5) ^ (a >> 8)) & 7) << 2);
}

__global__ __launch_bounds__(256, 4) void fwht_proj_kernel(
    const float* __restrict__ x,
    const float* __restrict__ scale,
    const float* __restrict__ bias,
    float* __restrict__ out)
{
    __shared__ float buf[4][N_IN];            // 32 KiB: private 8 KiB per wave
    __shared__ unsigned short blds[N_OUT];    // bf16 bias: 20,000 B

    // Stage bias once per block, f32 -> bf16 (RNE); err <= 1.5e-5 << 1.28e-3 thr
    {
        const f32x4* __restrict__ b4 = reinterpret_cast<const f32x4*>(bias);
        for (int i = threadIdx.x; i < N_OUT / 4; i += 256) {
            const f32x4 b = b4[i];
            u16x4 h;
            unsigned u;
            u = __float_as_uint(b.x); h.x = (unsigned short)((u + 0x7FFF + ((u >> 16) & 1)) >> 16);
            u = __float_as_uint(b.y); h.y = (unsigned short)((u + 0x7FFF + ((u >> 16) & 1)) >> 16);
            u = __float_as_uint(b.z); h.z = (unsigned short)((u + 0x7FFF + ((u >> 16) & 1)) >> 16);
            u = __float_as_uint(b.w); h.w = (unsigned short)((u + 0x7FFF + ((u >> 16) & 1)) >> 16);
            *reinterpret_cast<u16x4*>(&blds[i << 2]) = h;
        }
    }
    __syncthreads();

    const int wave = threadIdx.x >> 6;
    const int lane = threadIdx.x & 63;
    float* __restrict__ my = buf[wave];
    const size_t row = (size_t)blockIdx.x * 4 + wave;   // rows % 4 == 0
    const float* __restrict__ xrow = x + row * N_IN;

    // ---- load (layout A: e = j*256 + lane*4 + c) + sum of squares ----
    f32x4 v[8];
    float ss = 0.0f;
#pragma unroll
    for (int j = 0; j < 8; ++j) {
        v[j] = *reinterpret_cast<const f32x4*>(xrow + (j << 8) + (lane << 2));
        ss = fmaf(v[j].x, v[j].x, ss);
        ss = fmaf(v[j].y, v[j].y, ss);
        ss = fmaf(v[j].z, v[j].z, ss);
        ss = fmaf(v[j].w, v[j].w, ss);
    }
#pragma unroll
    for (int m = 1; m < 64; m <<= 1)
        ss += __shfl_xor(ss, m, 64);
    const float inv = 1.0f / (sqrtf(ss) + 1e-8f);   // matches x/(norm+eps)

    // ---- A-stages: bits 0,1 (inside each float4) ----
#pragma unroll
    for (int j = 0; j < 8; ++j) {
        const f32x4 a = v[j];
        f32x4 t;
        t.x = a.x + a.y;  t.y = a.x - a.y;
        t.z = a.z + a.w;  t.w = a.z - a.w;
        f32x4 u;
        u.x = t.x + t.z;  u.y = t.y + t.w;
        u.z = t.x - t.z;  u.w = t.y - t.w;
        v[j] = u;
    }
    // ---- A-stages: bits 8,9,10 (register index xor 1,2,4) ----
#pragma unroll
    for (int jm = 1; jm <= 4; jm <<= 1) {
#pragma unroll
        for (int j = 0; j < 8; ++j) {
            if ((j & jm) == 0) {
                const f32x4 a = v[j], b = v[j ^ jm];
                v[j]      = a + b;
                v[j ^ jm] = a - b;
            }
        }
    }

    // ---- transpose write: slot sigma(e) = lane + c1*64 + j*128 + c0*1024 ----
#pragma unroll
    for (int j = 0; j < 8; ++j) {
        my[swz(lane + (j << 7)       )] = v[j].x;   // c=0
        my[swz(lane + (j << 7) + 1024)] = v[j].y;   // c=1 (bit0 -> a[10])
        my[swz(lane + (j << 7) +   64)] = v[j].z;   // c=2 (bit1 -> a[6])
        my[swz(lane + (j << 7) + 1088)] = v[j].w;   // c=3
    }
    asm volatile("s_waitcnt lgkmcnt(0)" ::: "memory");
    // ---- transposed read (layout B): a = lane*32 + j*4 ----
#pragma unroll
    for (int j = 0; j < 8; ++j)
        v[j] = *reinterpret_cast<const f32x4*>(my + swz((lane << 5) + (j << 2)));

    // ---- B-stage bit 7: partner = lane xor 1 (single shuffle stage) ----
    {
        const bool lo = (lane & 1) == 0;
#pragma unroll
        for (int j = 0; j < 8; ++j) {
            f32x4 p;
            p.x = __shfl_xor(v[j].x, 1, 64);
            p.y = __shfl_xor(v[j].y, 1, 64);
            p.z = __shfl_xor(v[j].z, 1, 64);
            p.w = __shfl_xor(v[j].w, 1, 64);
            v[j] = lo ? (v[j] + p) : (p - v[j]);
        }
    }
    // ---- B-stages: bits 2,3 (inside each float4) ----
#pragma unroll
    for (int j = 0; j < 8; ++j) {
        const f32x4 a = v[j];
        f32x4 t;
        t.x = a.x + a.y;  t.y = a.x - a.y;
        t.z = a.z + a.w;  t.w = a.z - a.w;
        f32x4 u;
        u.x = t.x + t.z;  u.y = t.y + t.w;
        u.z = t.x - t.z;  u.w = t.y - t.w;
        v[j] = u;
    }
    // ---- B-stages: bits 4,5,6 (register index xor 1,2,4) ----
#pragma unroll
    for (int jm = 1; jm <= 4; jm <<= 1) {
#pragma unroll
        for (int j = 0; j < 8; ++j) {
            if ((j & jm) == 0) {
                const f32x4 a = v[j], b = v[j ^ jm];
                v[j]      = a + b;
                v[j ^ jm] = a - b;
            }
        }
    }

    // ---- y write-back at plain element index e (swizzled) ----
    const int ybase = ((lane & 1) << 7) | (lane & 2) | ((lane & 28) << 6) | ((lane >> 5) & 1);
#pragma unroll
    for (int j = 0; j < 8; ++j) {
        my[swz(ybase + (j << 4)     )] = v[j].x;
        my[swz(ybase + (j << 4) +  4)] = v[j].y;
        my[swz(ybase + (j << 4) +  8)] = v[j].z;
        my[swz(ybase + (j << 4) + 12)] = v[j].w;
    }
    asm volatile("s_waitcnt lgkmcnt(0)" ::: "memory");

    // ---- epilogue: y from LDS (swizzled linear), bf16 bias from LDS ----
    const float s = -scale[0] * inv;
    float* __restrict__ orow = out + row * N_OUT;

    int yo[8];                       // statically indexed after unroll
#pragma unroll
    for (int j = 0; j < 8; ++j)
        yo[j] = swz((j << 8) + (lane << 2));

#pragma unroll
    for (int w = 0; w < 4; ++w) {
#pragma unroll
        for (int j = 0; j < 8; ++j) {
            const int o = (w << 11) + (j << 8) + (lane << 2);
            const f32x4 y = *reinterpret_cast<const f32x4*>(my + yo[j]);
            const u16x4 h = *reinterpret_cast<const u16x4*>(&blds[o]);
            f32x4 r;
            r.x = fmaf(s, y.x, __uint_as_float((unsigned)h.x << 16));
            r.y = fmaf(s, y.y, __uint_as_float((unsigned)h.y << 16));
            r.z = fmaf(s, y.z, __uint_as_float((unsigned)h.z << 16));
            r.w = fmaf(s, y.w, __uint_as_float((unsigned)h.w << 16));
            *reinterpret_cast<f32x4*>(orow + o) = r;
        }
    }
    // partial window w=4: j=0..6 full, j=7 lanes 0..3
#pragma unroll
    for (int j = 0; j < 7; ++j) {
        const int o = 8192 + (j << 8) + (lane << 2);
        const f32x4 y = *reinterpret_cast<const f32x4*>(my + yo[j]);
        const u16x4 h = *reinterpret_cast<const u16x4*>(&blds[o]);
        f32x4 r;
        r.x = fmaf(s, y.x, __uint_as_float((unsigned)h.x << 16));
        r.y = fmaf(s, y.y, __uint_as_float((unsigned)h.y << 16));
        r.z = fmaf(s, y.z, __uint_as_float((unsigned)h.z << 16));
        r.w = fmaf(s, y.w, __uint_as_float((unsigned)h.w << 16));
        *reinterpret_cast<f32x4*>(orow + o) = r;
    }
    if (lane < 4) {
        const int o = 9984 + (lane << 2);
        const f32x4 y = *reinterpret_cast<const f32x4*>(my + yo[7]);
        const u16x4 h = *reinterpret_cast<const u16x4*>(&blds[o]);
        f32x4 r;
        r.x = fmaf(s, y.x, __uint_as_float((unsigned)h.x << 16));
        r.y = fmaf(s, y.y, __uint_as_float((unsigned)h.y << 16));
        r.z = fmaf(s, y.z, __uint_as_float((unsigned)h.z << 16));
        r.w = fmaf(s, y.w, __uint_as_float((unsigned)h.w << 16));
        *reinterpret_cast<f32x4*>(orow + o) = r;
    }
}

extern "C" void kernel_launch(void* const* d_in, const int* in_sizes, int n_in,
                              void* d_out, int out_size, void* d_ws, size_t ws_size,
                              hipStream_t stream) {
    const float* x     = (const float*)d_in[0];
    // d_in[1] = proj: unused — Hadamard structure computed via FWHT
    const float* scale = (const float*)d_in[2];
    const float* bias  = (const float*)d_in[3];
    float* out = (float*)d_out;

    const int rows = in_sizes[0] / N_IN;            // 16384
    dim3 grid(rows / 4), block(256);                // 4096 blocks
    hipLaunchKernelGGL(fwht_proj_kernel, grid, block, 0, stream,
                       x, scale, bias, out);
}